// Round 1
// baseline (672.086 us; speedup 1.0000x reference)
//
#include <hip/hip_runtime.h>

typedef __attribute__((ext_vector_type(8))) short short8;
typedef __attribute__((ext_vector_type(4))) float f32x4;

#define NSPLIT 64
#define NPTS   (16 * 1024 * 32)   // 524288 points
#define NCH    128

__device__ __forceinline__ short f2bf(float f) {
  unsigned u = __float_as_uint(f);
  u += 0x7fffu + ((u >> 16) & 1u);   // round-to-nearest-even bf16
  return (short)(u >> 16);
}

// ---------- prep: pack weights into MFMA B-fragment order; zero stats ----------
// Wpack layout: frag f = nb*4+kb (nb: 16-col block, kb: 32-k block), lane l, elem u:
//   wp[((f*64 + l)*8 + u)] = bf16( w[o=nb*16+(l&15)][k=kb*32+(l>>4)*8+u] )
__global__ __launch_bounds__(256) void k_prep(const float* __restrict__ w1,
                                              const float* __restrict__ w2,
                                              short* __restrict__ wp1,
                                              short* __restrict__ wp2,
                                              float* __restrict__ gstats) {
  int idx = blockIdx.x * 256 + threadIdx.x;
  if (idx < 16384) {
    int t = idx;
    int u = t & 7, l = (t >> 3) & 63, f = t >> 9;
    int nb = f >> 2, kb = f & 3;
    int o = nb * 16 + (l & 15);
    int k = kb * 32 + ((l >> 4) << 3) + u;
    wp1[t] = f2bf(w1[o * 128 + k]);
  } else if (idx < 32768) {
    int t = idx - 16384;
    int u = t & 7, l = (t >> 3) & 63, f = t >> 9;
    int nb = f >> 2, kb = f & 3;
    int o = nb * 16 + (l & 15);
    int k = kb * 32 + ((l >> 4) << 3) + u;
    wp2[t] = f2bf(w2[o * 128 + k]);
  } else if (idx < 32768 + 4 * NSPLIT * 128) {
    gstats[idx - 32768] = 0.0f;
  }
}

// ---------- finalize: per-channel scale/shift from accumulated sums ----------
__global__ __launch_bounds__(128) void k_finalize(const float* __restrict__ gsum,
                                                  const float* __restrict__ gsq,
                                                  const float* __restrict__ gamma,
                                                  const float* __restrict__ beta,
                                                  float* __restrict__ scale,
                                                  float* __restrict__ shift) {
  int c = threadIdx.x;
  float s = 0.f, q = 0.f;
  for (int sp = 0; sp < NSPLIT; ++sp) {
    s += gsum[sp * 128 + c];
    q += gsq[sp * 128 + c];
  }
  const float inv = 1.0f / (float)NPTS;
  float mean = s * inv;
  float var = q * inv - mean * mean;
  float rs = rsqrtf(var + 1e-5f);
  float sc = gamma[c] * rs;
  scale[c] = sc;
  shift[c] = beta[c] - mean * sc;
}

// ---------- main phase kernel ----------
// PHASE 1: h1 = x @ w1^T            -> accumulate per-channel sum/sumsq of h1
// PHASE 2: a1 = lrelu(bn1(h1)); h2 = a1 @ w2^T -> accumulate sum/sumsq of h2
// PHASE 3: y = lrelu(bn2(h2) + x); out = max over s=32
template <int PHASE>
__global__ __launch_bounds__(256, 2) void k_gemm(
    const float* __restrict__ x,
    const short* __restrict__ wp1, const short* __restrict__ wp2,
    const float* __restrict__ scale1, const float* __restrict__ shift1,
    const float* __restrict__ scale2, const float* __restrict__ shift2,
    float* __restrict__ gstats, float* __restrict__ out) {
  __shared__ short lw1[16384];                              // 32 KB
  __shared__ short lw2[(PHASE >= 2) ? 16384 : 16];          // 32 KB (ph2/3)
  __shared__ short stripes[(PHASE >= 2) ? 8192 : 2048];     // 16 KB a1 stripes / 4 KB redu

  const int tid = threadIdx.x;
  const int lane = tid & 63;
  const int wave = tid >> 6;
  const int l15 = lane & 15;
  const int l4 = lane >> 4;

  // stage packed weights into LDS (linear copy, layout preserved)
  {
    const int4* s1p = (const int4*)wp1;
    int4* d1p = (int4*)lw1;
    for (int i = tid; i < 2048; i += 256) d1p[i] = s1p[i];
    if (PHASE >= 2) {
      const int4* s2p = (const int4*)wp2;
      int4* d2p = (int4*)lw2;
      for (int i = tid; i < 2048; i += 256) d2p[i] = s2p[i];
    }
  }
  __syncthreads();

  float s1[8], sh1[8], s2[8], sh2[8];
  if (PHASE >= 2) {
#pragma unroll
    for (int nb = 0; nb < 8; ++nb) {
      s1[nb] = scale1[nb * 16 + l15];
      sh1[nb] = shift1[nb * 16 + l15];
    }
  }
  if (PHASE == 3) {
#pragma unroll
    for (int nb = 0; nb < 8; ++nb) {
      s2[nb] = scale2[nb * 16 + l15];
      sh2[nb] = shift2[nb * 16 + l15];
    }
  }

  float ssum[8], ssq[8], om0[8], om1[8];
#pragma unroll
  for (int nb = 0; nb < 8; ++nb) {
    ssum[nb] = 0.f; ssq[nb] = 0.f;
    om0[nb] = -3.4e38f; om1[nb] = -3.4e38f;
  }

  char* mystripe = (char*)(stripes) + wave * 4096;
  const int rowblk = blockIdx.x * 256;

  for (int rt = 0; rt < 4; ++rt) {
    const int row0 = rowblk + wave * 64 + rt * 16;
    // ---- A1 fragments direct from x (fp32 -> bf16) ----
    short8 afr[4];
    const float* xrow = x + (size_t)(row0 + l15) * 128 + l4 * 8;
#pragma unroll
    for (int kb = 0; kb < 4; ++kb) {
      float4 v0 = *(const float4*)(xrow + kb * 32);
      float4 v1 = *(const float4*)(xrow + kb * 32 + 4);
      short8 a;
      a[0] = f2bf(v0.x); a[1] = f2bf(v0.y); a[2] = f2bf(v0.z); a[3] = f2bf(v0.w);
      a[4] = f2bf(v1.x); a[5] = f2bf(v1.y); a[6] = f2bf(v1.z); a[7] = f2bf(v1.w);
      afr[kb] = a;
    }
    // ---- mm1 ----
#pragma unroll
    for (int nb = 0; nb < 8; ++nb) {
      f32x4 acc = {0.f, 0.f, 0.f, 0.f};
#pragma unroll
      for (int kb = 0; kb < 4; ++kb) {
        short8 b = *(const short8*)(lw1 + ((nb * 4 + kb) * 64 + lane) * 8);
        acc = __builtin_amdgcn_mfma_f32_16x16x32_bf16(afr[kb], b, acc, 0, 0, 0);
      }
      if (PHASE == 1) {
#pragma unroll
        for (int j = 0; j < 4; ++j) {
          float h = acc[j];
          ssum[nb] += h;
          ssq[nb] += h * h;
        }
      } else {
        // bn1 + leaky relu -> swizzled wave-private LDS stripe [16 rows][128 ch] bf16
#pragma unroll
        for (int j = 0; j < 4; ++j) {
          float v = acc[j] * s1[nb] + sh1[nb];
          v = v > 0.f ? v : 0.01f * v;
          int p = l4 * 4 + j;
          int cb = (nb * 16 + l15) * 2;
          int off = (p << 8) | ((((cb >> 4) ^ (p & 7)) << 4) | (cb & 15));
          *(short*)(mystripe + off) = f2bf(v);
        }
      }
    }
    if (PHASE >= 2) {
      // ---- A2 fragments from stripe (swizzled read; row = l15) ----
      short8 a2[4];
#pragma unroll
      for (int kb = 0; kb < 4; ++kb) {
        int chunk = (kb * 4 + l4) ^ (l15 & 7);
        int off = (l15 << 8) | (chunk << 4);
        a2[kb] = *(const short8*)(mystripe + off);
      }
      // ---- mm2 ----
#pragma unroll
      for (int nb = 0; nb < 8; ++nb) {
        f32x4 acc = {0.f, 0.f, 0.f, 0.f};
#pragma unroll
        for (int kb = 0; kb < 4; ++kb) {
          short8 b = *(const short8*)(lw2 + ((nb * 4 + kb) * 64 + lane) * 8);
          acc = __builtin_amdgcn_mfma_f32_16x16x32_bf16(a2[kb], b, acc, 0, 0, 0);
        }
        if (PHASE == 2) {
#pragma unroll
          for (int j = 0; j < 4; ++j) {
            float h = acc[j];
            ssum[nb] += h;
            ssq[nb] += h * h;
          }
        } else {
#pragma unroll
          for (int j = 0; j < 4; ++j) {
            int p = l4 * 4 + j;
            float xr = x[(size_t)(row0 + p) * 128 + nb * 16 + l15];
            float v = acc[j] * s2[nb] + sh2[nb] + xr;
            v = v > 0.f ? v : 0.01f * v;
            if (rt < 2) om0[nb] = fmaxf(om0[nb], v);
            else        om1[nb] = fmaxf(om1[nb], v);
          }
        }
      }
    }
  }

  if (PHASE <= 2) {
    __syncthreads();                      // stripes consumed; reuse as reduction area
    float* redu = (float*)stripes;        // [4 waves][128 ch][2]
#pragma unroll
    for (int nb = 0; nb < 8; ++nb) {
      float a = ssum[nb], b = ssq[nb];
      a += __shfl_xor(a, 16, 64); a += __shfl_xor(a, 32, 64);
      b += __shfl_xor(b, 16, 64); b += __shfl_xor(b, 32, 64);
      if (l4 == 0) {
        int c = nb * 16 + l15;
        redu[(wave * 128 + c) * 2 + 0] = a;
        redu[(wave * 128 + c) * 2 + 1] = b;
      }
    }
    __syncthreads();
    if (tid < 128) {
      float s = 0.f, q = 0.f;
#pragma unroll
      for (int w = 0; w < 4; ++w) {
        s += redu[(w * 128 + tid) * 2 + 0];
        q += redu[(w * 128 + tid) * 2 + 1];
      }
      int split = blockIdx.x & (NSPLIT - 1);
      int base = (PHASE == 1 ? 0 : 2) * NSPLIT * 128;
      atomicAdd(&gstats[base + split * 128 + tid], s);
      atomicAdd(&gstats[base + NSPLIT * 128 + split * 128 + tid], q);
    }
  } else {
    const int bn0 = (rowblk + wave * 64) >> 5;   // wave's 64 rows = 2 bn-groups
#pragma unroll
    for (int nb = 0; nb < 8; ++nb) {
      float m0 = om0[nb], m1 = om1[nb];
      m0 = fmaxf(m0, __shfl_xor(m0, 16, 64)); m0 = fmaxf(m0, __shfl_xor(m0, 32, 64));
      m1 = fmaxf(m1, __shfl_xor(m1, 16, 64)); m1 = fmaxf(m1, __shfl_xor(m1, 32, 64));
      int c = nb * 16 + l15;
      if (l4 == 0)      out[(size_t)bn0 * 128 + c] = m0;
      else if (l4 == 1) out[(size_t)(bn0 + 1) * 128 + c] = m1;
    }
  }
}

extern "C" void kernel_launch(void* const* d_in, const int* in_sizes, int n_in,
                              void* d_out, int out_size, void* d_ws, size_t ws_size,
                              hipStream_t stream) {
  const float* x   = (const float*)d_in[0];
  const float* w1  = (const float*)d_in[1];
  // d_in[2] = b1 (unused: constant per-channel bias cancels inside BatchNorm)
  const float* g1  = (const float*)d_in[3];
  const float* be1 = (const float*)d_in[4];
  const float* w2  = (const float*)d_in[5];
  // d_in[6] = b2 (unused, same reason)
  const float* g2  = (const float*)d_in[7];
  const float* be2 = (const float*)d_in[8];
  float* out = (float*)d_out;

  char* ws = (char*)d_ws;
  short* wp1 = (short*)ws;                       // 32 KB
  short* wp2 = (short*)(ws + 32768);             // 32 KB
  float* gstats = (float*)(ws + 65536);          // 4 * NSPLIT * 128 floats = 128 KB
  float* scale1 = (float*)(ws + 65536 + 4 * NSPLIT * 128 * 4);
  float* shift1 = scale1 + 128;
  float* scale2 = scale1 + 256;
  float* shift2 = scale1 + 384;

  k_prep<<<256, 256, 0, stream>>>(w1, w2, wp1, wp2, gstats);

  k_gemm<1><<<NPTS / 256, 256, 0, stream>>>(x, wp1, wp2, scale1, shift1, scale2,
                                            shift2, gstats, out);
  k_finalize<<<1, 128, 0, stream>>>(gstats, gstats + NSPLIT * 128, g1, be1,
                                    scale1, shift1);
  k_gemm<2><<<NPTS / 256, 256, 0, stream>>>(x, wp1, wp2, scale1, shift1, scale2,
                                            shift2, gstats, out);
  k_finalize<<<1, 128, 0, stream>>>(gstats + 2 * NSPLIT * 128,
                                    gstats + 3 * NSPLIT * 128, g2, be2,
                                    scale2, shift2);
  k_gemm<3><<<NPTS / 256, 256, 0, stream>>>(x, wp1, wp2, scale1, shift1, scale2,
                                            shift2, gstats, out);
}